// Round 8
// baseline (175.671 us; speedup 1.0000x reference)
//
#include <hip/hip_runtime.h>

#define BB 2
#define NN 2048
#define EE 768
#define HH 12
#define DD 64
#define MM (BB*NN)      // 4096
#define E3 (3*EE)       // 2304
// 1/sqrt(768) * log2(e): scores in log2 domain -> P = exp2(s)
#define QSCALE 0.05205877280961602f

typedef __bf16 bf16x8 __attribute__((ext_vector_type(8)));
typedef float  f32x4  __attribute__((ext_vector_type(4)));
typedef unsigned short u16x8 __attribute__((ext_vector_type(8)));

#define MFMA(a,b,c) __builtin_amdgcn_mfma_f32_16x16x32_bf16(a,b,c,0,0,0)

__device__ __forceinline__ unsigned short f2bf(float f) {
    unsigned int u = __float_as_uint(f);
    u += 0x7FFFu + ((u >> 16) & 1u);     // round-to-nearest-even
    return (unsigned short)(u >> 16);
}

typedef __attribute__((address_space(3))) unsigned int as3u32;
typedef __attribute__((address_space(1))) unsigned int as1u32;
__device__ __forceinline__ void gll16(const void* g, void* l) {
    // lane i deposits its 16B at lds_base + i*16 (wave-uniform dest base)
    __builtin_amdgcn_global_load_lds((const as1u32*)(uintptr_t)g,
                                     (as3u32*)(unsigned int)(uintptr_t)l, 16, 0, 0);
}

// ---------------------------------------------------------------------------
// fused f32 -> bf16 cast of x, w_qkv, w_o (contiguous dsts in ws)
// ---------------------------------------------------------------------------
#define XB4 786432   // (MM*EE)/4
#define WQ4 442368   // (E3*EE)/4
#define WO4 147456   // (EE*EE)/4
__global__ __launch_bounds__(256)
void cast3(const float* __restrict__ x, const float* __restrict__ wq,
           const float* __restrict__ wo, unsigned short* __restrict__ dst) {
    int i = blockIdx.x * 256 + threadIdx.x;
    const float* src;
    int off;
    if (i < XB4)            { src = x;  off = i; }
    else if (i < XB4+WQ4)   { src = wq; off = i - XB4; }
    else                    { src = wo; off = i - XB4 - WQ4; }
    float4 v = ((const float4*)src)[off];
    ushort4 o;
    o.x = f2bf(v.x); o.y = f2bf(v.y); o.z = f2bf(v.z); o.w = f2bf(v.w);
    ((ushort4*)dst)[i] = o;
}

// ---------------------------------------------------------------------------
// QKV GEMM: 128x128 tile, BK=32, 4 waves, wave 64x64.
// Scatter: q TRANSPOSED+scaled [B][H][D][N], k [B][H][N][D],
//          v TRANSPOSED [B][H][D][N]  (packed ushort4 stores along N for q,v)
// ---------------------------------------------------------------------------
__global__ __launch_bounds__(256)
void gemm_qkv(const unsigned short* __restrict__ A, const unsigned short* __restrict__ W,
              const float* __restrict__ bias,
              unsigned short* __restrict__ o0, unsigned short* __restrict__ o1,
              unsigned short* __restrict__ o2)
{
    __shared__ unsigned short As[128 * 32];
    __shared__ unsigned short Bs[128 * 32];

    const int tid = threadIdx.x;
    const int l = tid & 63;
    const int w = tid >> 6;
    const int m0 = blockIdx.x * 128;
    const int c0 = blockIdx.y * 128;
    const int wm = (w >> 1) * 64;
    const int wn = (w & 1) * 64;

    const int s0 = w * 2;
    const unsigned short* a_src0 = A + (size_t)(m0 + s0*16      + (l>>2)) * EE + (l&3)*8;
    const unsigned short* a_src1 = A + (size_t)(m0 + (s0+1)*16  + (l>>2)) * EE + (l&3)*8;
    const unsigned short* b_src0 = W + (size_t)(c0 + s0*16      + (l>>2)) * EE + (l&3)*8;
    const unsigned short* b_src1 = W + (size_t)(c0 + (s0+1)*16  + (l>>2)) * EE + (l&3)*8;
    unsigned short* a_dst0 = &As[s0*512];
    unsigned short* a_dst1 = &As[(s0+1)*512];
    unsigned short* b_dst0 = &Bs[s0*512];
    unsigned short* b_dst1 = &Bs[(s0+1)*512];

    const f32x4 zero4 = {0.f, 0.f, 0.f, 0.f};
    f32x4 acc[4][4];
    #pragma unroll
    for (int i = 0; i < 4; ++i)
        #pragma unroll
        for (int j = 0; j < 4; ++j) acc[i][j] = zero4;

    for (int k0 = 0; k0 < EE; k0 += 32) {
        __syncthreads();
        gll16(a_src0 + k0, a_dst0);
        gll16(a_src1 + k0, a_dst1);
        gll16(b_src0 + k0, b_dst0);
        gll16(b_src1 + k0, b_dst1);
        __syncthreads();

        bf16x8 af[4], bf[4];
        #pragma unroll
        for (int i = 0; i < 4; ++i)
            af[i] = *(const bf16x8*)&As[(wm + 16*i + (l&15))*32 + (l>>4)*8];
        #pragma unroll
        for (int j = 0; j < 4; ++j)
            bf[j] = *(const bf16x8*)&Bs[(wn + 16*j + (l&15))*32 + (l>>4)*8];
        #pragma unroll
        for (int i = 0; i < 4; ++i)
            #pragma unroll
            for (int j = 0; j < 4; ++j)
                acc[i][j] = MFMA(af[i], bf[j], acc[i][j]);
    }

    // epilogue: C/D col = l&15, row = (l>>4)*4 + r. wn section = one (h,t).
    const int sec = (c0 + wn) >> 6;        // = hh*3 + tt
    const int hh = sec / 3;
    const int tt = sec - hh*3;
    #pragma unroll
    for (int j = 0; j < 4; ++j) {
        const int col = c0 + wn + 16*j + (l&15);
        const int dcol = 16*j + (l&15);
        const float bj = bias[col];
        #pragma unroll
        for (int i = 0; i < 4; ++i) {
            const int row0 = m0 + wm + 16*i + (l>>4)*4;
            const int b = row0 >> 11;
            const int n = row0 & (NN - 1);
            if (tt != 1) {
                // q and v transposed: [B][H][D][N], 4 consecutive n -> packed
                unsigned short* dst = (tt == 0) ? o0 : o2;
                const float scl = (tt == 0) ? QSCALE : 1.f;
                ushort4 pk;
                pk.x = f2bf((acc[i][j][0] + bj) * scl);
                pk.y = f2bf((acc[i][j][1] + bj) * scl);
                pk.z = f2bf((acc[i][j][2] + bj) * scl);
                pk.w = f2bf((acc[i][j][3] + bj) * scl);
                *(ushort4*)&dst[(((size_t)b*HH + hh)*DD + dcol)*NN + n] = pk;
            } else {
                #pragma unroll
                for (int r = 0; r < 4; ++r) {
                    o1[(((size_t)b*HH + hh)*NN + n + r)*DD + dcol] =
                        f2bf(acc[i][j][r] + bj);
                }
            }
        }
    }
}

// ---------------------------------------------------------------------------
// Output GEMM: 64x128 tile, BK=32, 4 waves, wave tile 32x64 (2x4 frags).
// ---------------------------------------------------------------------------
__global__ __launch_bounds__(256)
void gemm_out(const unsigned short* __restrict__ A, const unsigned short* __restrict__ W,
              const float* __restrict__ bias, float* __restrict__ of)
{
    __shared__ unsigned short As[64 * 32];    // 4 KB
    __shared__ unsigned short Bs[128 * 32];   // 8 KB

    const int tid = threadIdx.x;
    const int l = tid & 63;
    const int w = tid >> 6;
    const int m0 = blockIdx.x * 64;
    const int c0 = blockIdx.y * 128;
    const int wm = (w >> 1) * 32;
    const int wn = (w & 1) * 64;

    const unsigned short* s_src[3];
    unsigned short* s_dst[3];
    #pragma unroll
    for (int s = 0; s < 3; ++s) {
        const int ch = 3*w + s;
        if (ch < 4) {
            s_src[s] = A + (size_t)(m0 + ch*16 + (l>>2)) * EE + (l&3)*8;
            s_dst[s] = &As[ch*512];
        } else {
            s_src[s] = W + (size_t)(c0 + (ch-4)*16 + (l>>2)) * EE + (l&3)*8;
            s_dst[s] = &Bs[(ch-4)*512];
        }
    }

    const f32x4 zero4 = {0.f, 0.f, 0.f, 0.f};
    f32x4 acc[2][4];
    #pragma unroll
    for (int i = 0; i < 2; ++i)
        #pragma unroll
        for (int j = 0; j < 4; ++j) acc[i][j] = zero4;

    for (int k0 = 0; k0 < EE; k0 += 32) {
        __syncthreads();
        #pragma unroll
        for (int s = 0; s < 3; ++s) gll16(s_src[s] + k0, s_dst[s]);
        __syncthreads();

        bf16x8 af[2], bf[4];
        #pragma unroll
        for (int i = 0; i < 2; ++i)
            af[i] = *(const bf16x8*)&As[(wm + 16*i + (l&15))*32 + (l>>4)*8];
        #pragma unroll
        for (int j = 0; j < 4; ++j)
            bf[j] = *(const bf16x8*)&Bs[(wn + 16*j + (l&15))*32 + (l>>4)*8];
        #pragma unroll
        for (int i = 0; i < 2; ++i)
            #pragma unroll
            for (int j = 0; j < 4; ++j)
                acc[i][j] = MFMA(af[i], bf[j], acc[i][j]);
    }

    #pragma unroll
    for (int j = 0; j < 4; ++j) {
        const int col = c0 + wn + 16*j + (l&15);
        const float bj = bias[col];
        #pragma unroll
        for (int i = 0; i < 2; ++i) {
            #pragma unroll
            for (int r = 0; r < 4; ++r) {
                const int row = m0 + wm + 16*i + (l>>4)*4 + r;
                of[(size_t)row * EE + col] = acc[i][j][r] + bj;
            }
        }
    }
}

// ---------------------------------------------------------------------------
// MFMA flash attention, software-pipelined staging.
// Per iter: [bar; ds_write(regs loaded LAST iter); bar; issue loads(kt+1);
//            compute(kt)]  -> staging loads age a full compute phase before
// any barrier drains vmcnt (the r7 structure exposed full L2 latency/iter).
// Block = 64 Q of one (b,h), 4 waves x 16 q. Grid 768: bh = id%24 (XCD-grouped).
// S^T = K*Q^T, per-lane no-max softmax, deferred denominator.
// Q arrives TRANSPOSED [B][H][D][N] (one-time scalar frag gather).
// Ks/Vt: [row][64], 16B-chunk ^ (row&7); Pq per-wave, 8B-chunk ^ (q&14).
// ---------------------------------------------------------------------------
__global__ __launch_bounds__(256)
void attn_mfma(const unsigned short* __restrict__ Qt_g, const unsigned short* __restrict__ K,
               const unsigned short* __restrict__ Vt_g, unsigned short* __restrict__ ctx)
{
    __shared__ unsigned short Ks[64 * 64];       // 8 KB
    __shared__ unsigned short Vt[64 * 64];       // 8 KB
    __shared__ unsigned short Pq[4 * 16 * 64];   // 8 KB, per-wave [q=16][64]

    const int tid = threadIdx.x;
    const int l = tid & 63;
    const int w = tid >> 6;
    const int quad = l >> 4;
    const int lc = l & 15;
    const int x7 = lc & 7;

    const int id = blockIdx.x;
    const int bh = id % 24;              // b*HH + h
    const int bq = id / 24;              // q-tile
    const int b  = bh / 12;
    const int h  = bh - b*12;
    const size_t hb = (size_t)bh * NN * DD;

    const f32x4 zero4 = {0.f, 0.f, 0.f, 0.f};

    // Q B-frags from transposed Q (one-time scalar gather, pre-scaled)
    const int qrow = bq*64 + w*16 + lc;
    u16x8 q0r, q1r;
    #pragma unroll
    for (int j = 0; j < 8; ++j) {
        q0r[j] = Qt_g[hb + (size_t)(     quad*8 + j)*NN + qrow];
        q1r[j] = Qt_g[hb + (size_t)(32 + quad*8 + j)*NN + qrow];
    }
    const bf16x8 qf0 = __builtin_bit_cast(bf16x8, q0r);
    const bf16x8 qf1 = __builtin_bit_cast(bf16x8, q1r);

    f32x4 o[4];
    #pragma unroll
    for (int dj = 0; dj < 4; ++dj) o[dj] = zero4;
    float lsum = 0.f;

    // staging: 256 threads, row = tid>>2 (64 rows), sc = tid&3 (2 chunks)
    const int srow = tid >> 2;
    const int sc = tid & 3;
    const unsigned short* kbase = K + hb + (size_t)srow*DD + sc*16;
    const unsigned short* vbase = Vt_g + hb + (size_t)srow*NN + sc*16;
    const int c0s = ((2*sc)     ^ (srow & 7)) * 8;
    const int c1s = ((2*sc + 1) ^ (srow & 7)) * 8;
    const int so = srow * 64;

    // frag-read swizzled chunk offsets
    const int chq0 = ((    quad) ^ x7) * 8;
    const int chq1 = ((4 + quad) ^ x7) * 8;
    const int pw = w * 1024;
    const int prd0 = pw + lc*64 + (((    2*quad) ^ (lc & 14)) * 4);
    const int prd1 = pw + lc*64 + (((8 + 2*quad) ^ (lc & 14)) * 4);

    // staging regs (tile in flight)
    u16x8 rk0, rk1, rv0, rv1;
    {
        const unsigned short* kp = kbase;
        const unsigned short* vp = vbase;
        rk0 = *(const u16x8*)kp;
        rk1 = *(const u16x8*)(kp + 8);
        rv0 = *(const u16x8*)vp;
        rv1 = *(const u16x8*)(vp + 8);
    }

    for (int kt = 0; kt < NN/64; ++kt) {
        __syncthreads();                 // prior-iter readers done
        *(u16x8*)&Ks[so + c0s] = rk0;    // waits vmcnt of loads issued LAST iter
        *(u16x8*)&Ks[so + c1s] = rk1;
        *(u16x8*)&Vt[so + c0s] = rv0;
        *(u16x8*)&Vt[so + c1s] = rv1;
        __syncthreads();                 // writers done

        // issue next-tile loads; they age through compute before next barrier
        {
            const int ktn = (kt + 1 < NN/64) ? kt + 1 : kt;
            const unsigned short* kp = kbase + (size_t)ktn*64*DD;
            const unsigned short* vp = vbase + ktn*64;
            rk0 = *(const u16x8*)kp;
            rk1 = *(const u16x8*)(kp + 8);
            rv0 = *(const u16x8*)vp;
            rv1 = *(const u16x8*)(vp + 8);
        }

        // S^T = K Q^T : A = K-frag, B = Q-frag. 4 key-frags x 2 k-steps.
        f32x4 st[4];
        #pragma unroll
        for (int jf = 0; jf < 4; ++jf) {
            bf16x8 kf0 = *(const bf16x8*)&Ks[(16*jf + lc)*64 + chq0];
            bf16x8 kf1 = *(const bf16x8*)&Ks[(16*jf + lc)*64 + chq1];
            f32x4 acc0 = MFMA(kf0, qf0, zero4);
            st[jf] = MFMA(kf1, qf1, acc0);
        }

        // P = exp2(S^T). C layout: lane holds keys 16*jf + quad*4 + r, q = lc.
        #pragma unroll
        for (int jf = 0; jf < 4; ++jf) {
            float e0 = __builtin_amdgcn_exp2f(st[jf][0]);
            float e1 = __builtin_amdgcn_exp2f(st[jf][1]);
            float e2 = __builtin_amdgcn_exp2f(st[jf][2]);
            float e3 = __builtin_amdgcn_exp2f(st[jf][3]);
            lsum += (e0 + e1) + (e2 + e3);
            ushort4 pk;
            pk.x = f2bf(e0); pk.y = f2bf(e1); pk.z = f2bf(e2); pk.w = f2bf(e3);
            *(ushort4*)&Pq[pw + lc*64 + (((4*jf + quad) ^ (lc & 14)) * 4)] = pk;
        }

        // O^T += V^T P^T : A = V^T-frag, B = P^T-frag (b128, same wave)
        {
            bf16x8 pf0 = *(const bf16x8*)&Pq[prd0];
            bf16x8 pf1 = *(const bf16x8*)&Pq[prd1];
            #pragma unroll
            for (int dj = 0; dj < 4; ++dj) {
                bf16x8 vf0 = *(const bf16x8*)&Vt[(16*dj + lc)*64 + chq0];
                bf16x8 vf1 = *(const bf16x8*)&Vt[(16*dj + lc)*64 + chq1];
                o[dj] = MFMA(vf0, pf0, o[dj]);
                o[dj] = MFMA(vf1, pf1, o[dj]);
            }
        }
    }

    // final denominator: reduce across the 4 quads (same q = lc)
    lsum += __shfl_xor(lsum, 16);
    lsum += __shfl_xor(lsum, 32);
    const float inv = 1.f / lsum;

    // O^T C-layout: row = d = 16*dj + quad*4 + r, col = q = lc -> packed store
    const int n = bq*64 + w*16 + lc;
    #pragma unroll
    for (int dj = 0; dj < 4; ++dj) {
        ushort4 pk;
        pk.x = f2bf(o[dj][0] * inv);
        pk.y = f2bf(o[dj][1] * inv);
        pk.z = f2bf(o[dj][2] * inv);
        pk.w = f2bf(o[dj][3] * inv);
        *(ushort4*)&ctx[((size_t)(b*NN + n))*EE + h*DD + 16*dj + quad*4] = pk;
    }
}

// ---------------------------------------------------------------------------
extern "C" void kernel_launch(void* const* d_in, const int* in_sizes, int n_in,
                              void* d_out, int out_size, void* d_ws, size_t ws_size,
                              hipStream_t stream)
{
    const float* x     = (const float*)d_in[0];
    const float* w_qkv = (const float*)d_in[1];
    const float* b_qkv = (const float*)d_in[2];
    const float* w_o   = (const float*)d_in[3];
    const float* b_o   = (const float*)d_in[4];
    float* out = (float*)d_out;

    unsigned short* wsu = (unsigned short*)d_ws;
    const size_t XB = (size_t)MM * EE;
    const size_t WQ = (size_t)E3 * EE;
    const size_t WO = (size_t)EE * EE;
    const size_t HS = (size_t)BB * HH * NN * DD;
    unsigned short* xb   = wsu;
    unsigned short* wqb  = xb  + XB;
    unsigned short* wob  = wqb + WQ;
    unsigned short* qtb  = wob + WO;      // [B][H][D][N] (transposed, scaled)
    unsigned short* kb   = qtb + HS;      // [B][H][N][D]
    unsigned short* vtb  = kb  + HS;      // [B][H][D][N]
    unsigned short* ctxb = vtb + HS;

    cast3<<<(XB4 + WQ4 + WO4)/256, 256, 0, stream>>>(x, w_qkv, w_o, xb);

    dim3 g1(MM/128, E3/128);   // 32 x 18 = 576 blocks
    gemm_qkv<<<g1, 256, 0, stream>>>(xb, wqb, b_qkv, qtb, kb, vtb);

    attn_mfma<<<768, 256, 0, stream>>>(qtb, kb, vtb, ctxb);

    dim3 g3(MM/64, EE/128);    // 64 x 6 = 384 blocks
    gemm_out<<<g3, 256, 0, stream>>>(ctxb, wob, b_o, out);
}